// Round 1
// baseline (49.470 us; speedup 1.0000x reference)
//
#include <hip/hip_runtime.h>

// Welford mean/variance over batch dim.
// x: (B=64, C=64, H=128, W=128) fp32; m0,s0: (C,H,W) fp32; n0: int scalar.
// out: (2, C, H, W) fp32 = [m; s].

#define B_DIM 64
#define CHW (64 * 128 * 128)   // 1,048,576

__global__ __launch_bounds__(256) void welford_kernel(
    const float* __restrict__ x,
    const float* __restrict__ m0,
    const float* __restrict__ s0,
    const int* __restrict__ n0p,
    float* __restrict__ out)
{
    const int t = blockIdx.x * blockDim.x + threadIdx.x;  // float4 column index
    const int stride4 = CHW / 4;
    if (t >= stride4) return;

    const float4* __restrict__ x4 = (const float4*)x;
    float4 m = ((const float4*)m0)[t];
    float4 s = ((const float4*)s0)[t];
    float n = (float)(*n0p);   // uniform scalar load, L2-broadcast

    #pragma unroll 4
    for (int b = 0; b < B_DIM; ++b) {
        float4 xi = x4[b * stride4 + t];
        float inv = 1.0f / (n + 1.0f);   // exact fp32 division, matches reference
        float d;
        d = xi.x - m.x; m.x += d * inv; s.x += (xi.x - m.x) * d;
        d = xi.y - m.y; m.y += d * inv; s.y += (xi.y - m.y) * d;
        d = xi.z - m.z; m.z += d * inv; s.z += (xi.z - m.z) * d;
        d = xi.w - m.w; m.w += d * inv; s.w += (xi.w - m.w) * d;
        n += 1.0f;
    }

    float4* out4 = (float4*)out;
    out4[t] = m;                 // mean block
    out4[stride4 + t] = s;       // M2 block
}

extern "C" void kernel_launch(void* const* d_in, const int* in_sizes, int n_in,
                              void* d_out, int out_size, void* d_ws, size_t ws_size,
                              hipStream_t stream) {
    const float* x  = (const float*)d_in[0];
    const float* m0 = (const float*)d_in[1];
    const float* s0 = (const float*)d_in[2];
    const int*   n0 = (const int*)d_in[3];
    float* out = (float*)d_out;

    const int cols4 = CHW / 4;           // 262,144 float4 columns
    const int block = 256;
    const int grid = (cols4 + block - 1) / block;  // 1024 blocks
    welford_kernel<<<grid, block, 0, stream>>>(x, m0, s0, n0, out);
}